// Round 12
// baseline (329.979 us; speedup 1.0000x reference)
//
#include <hip/hip_runtime.h>
#include <math.h>

#define NPIX 4096
#define KN 20
#define MTOT 327680.0    // B*N*K

__device__ inline unsigned long long shflx64(unsigned long long v, int m) {
  unsigned lo = (unsigned)v, hi = (unsigned)(v >> 32);
  lo = __shfl_xor(lo, m, 64);
  hi = __shfl_xor(hi, m, 64);
  return (((unsigned long long)hi) << 32) | lo;
}

// ===== K1: conv1 (5x5,1->64,tanh, zero-outside) + conv2 (3x3,64->32,tanh) =====
// 8x8 tile, 512 thr. Channels-last LDS for conv1 output -> conv2 reads float4.
__global__ __launch_bounds__(512) void conv12_k(const float* __restrict__ x,
    const float* __restrict__ c1w, const float* __restrict__ c1b,
    const float* __restrict__ c2w, const float* __restrict__ c2b,
    float* __restrict__ c2buf) {
  __shared__ float sx[230];          // 14x14 halo, stride 16
  __shared__ float sc1[6800];        // 100 px (10x10) x 68 (64 ch + pad) = 27.2KB
  const int tid = threadIdx.x;
  const int l = tid & 63;
  const int w = __builtin_amdgcn_readfirstlane(tid >> 6);   // 8 waves, uniform
  const int b = blockIdx.x, tile = blockIdx.y;
  const int th = (tile >> 3) << 3, tw = (tile & 7) << 3;

  for (int i = tid; i < 196; i += 512) {
    int r = i / 14, c = i - r*14;
    int gr = th - 3 + r, gc = tw - 3 + c;
    sx[r*16 + c] = (gr>=0 && gr<64 && gc>=0 && gc<64) ? x[b*NPIX + (gr<<6) + gc] : 0.f;
  }
  __syncthreads();
  // conv1 on 10x10 halo region; wave w -> couts w*8..+7; channels-last store
  for (int half = 0; half < 2; half++) {
    int px = l + (half << 6);
    if (px < 100) {
      int i = px / 10, j = px - i*10;
      int gy = th - 1 + i, gx = tw - 1 + j;
      bool inb = (gy>=0 && gy<64 && gx>=0 && gx<64);
      for (int cc = 0; cc < 8; cc++) {
        int co = (w << 3) + cc;
        float acc = c1b[co];
#pragma unroll
        for (int di=0; di<5; di++)
#pragma unroll
          for (int dj=0; dj<5; dj++)
            acc = fmaf(sx[(i+di)*16 + j+dj], c1w[co*25 + di*5 + dj], acc);
        sc1[px*68 + co] = inb ? tanhf(acc) : 0.f;
      }
    }
  }
  __syncthreads();
  // conv2 exact 8x8: lane -> pixel; wave -> couts w*4..+3; float4 cin reads
  {
    int py = l >> 3, px2 = l & 7;
    int co0 = w << 2;
    const float* w0p = c2w + (size_t)(co0+0)*576;
    const float* w1p = c2w + (size_t)(co0+1)*576;
    const float* w2p = c2w + (size_t)(co0+2)*576;
    const float* w3p = c2w + (size_t)(co0+3)*576;
    float acc0 = c2b[co0+0], acc1 = c2b[co0+1], acc2 = c2b[co0+2], acc3 = c2b[co0+3];
#pragma unroll
    for (int di=0; di<3; di++)
#pragma unroll
      for (int dj=0; dj<3; dj++) {
        int tlin = di*3 + dj;
        const float* vp = sc1 + ((py+di)*10 + px2+dj)*68;
#pragma unroll
        for (int c4=0; c4<16; c4++) {
          float4 v = *(const float4*)(vp + (c4<<2));
          int wi = (c4<<2)*9 + tlin;
          acc0 = fmaf(v.x, w0p[wi], acc0);       acc1 = fmaf(v.x, w1p[wi], acc1);
          acc2 = fmaf(v.x, w2p[wi], acc2);       acc3 = fmaf(v.x, w3p[wi], acc3);
          acc0 = fmaf(v.y, w0p[wi+9], acc0);     acc1 = fmaf(v.y, w1p[wi+9], acc1);
          acc2 = fmaf(v.y, w2p[wi+9], acc2);     acc3 = fmaf(v.y, w3p[wi+9], acc3);
          acc0 = fmaf(v.z, w0p[wi+18], acc0);    acc1 = fmaf(v.z, w1p[wi+18], acc1);
          acc2 = fmaf(v.z, w2p[wi+18], acc2);    acc3 = fmaf(v.z, w3p[wi+18], acc3);
          acc0 = fmaf(v.w, w0p[wi+27], acc0);    acc1 = fmaf(v.w, w1p[wi+27], acc1);
          acc2 = fmaf(v.w, w2p[wi+27], acc2);    acc3 = fmaf(v.w, w3p[wi+27], acc3);
        }
      }
    size_t base = (((size_t)b*32 + co0) << 12) + ((th+py)<<6) + (tw+px2);
    c2buf[base]            = tanhf(acc0);
    c2buf[base + (1<<12)]  = tanhf(acc1);
    c2buf[base + (2<<12)]  = tanhf(acc2);
    c2buf[base + (3<<12)]  = tanhf(acc3);
  }
}

// ===== K2: conv3 (3x3,32->16,tanh, zero-outside) + conv4 (3x3,16->1) =====
// 8x8 tile, 512 thr. Channels-last LDS throughout, float4 cin reads.
__global__ __launch_bounds__(512) void conv34_k(const float* __restrict__ c2buf,
    const float* __restrict__ c3w, const float* __restrict__ c3b,
    const float* __restrict__ c4w, const float* __restrict__ c4b,
    float* __restrict__ fbuf) {
  __shared__ float sc2[5184];        // 144 px (12x12) x 36 (32 ch + pad) = 20.7KB
  __shared__ float sc3[2000];        // 100 px (10x10) x 20 (16 ch + pad) = 8KB
  const int tid = threadIdx.x;
  const int l = tid & 63;
  const int w = __builtin_amdgcn_readfirstlane(tid >> 6);
  const int b = blockIdx.x, tile = blockIdx.y;
  const int th = (tile >> 3) << 3, tw = (tile & 7) << 3;

  for (int i = tid; i < 4608; i += 512) {
    int cin = i / 144, pxh = i - cin*144;
    int rr = pxh / 12, cc = pxh - rr*12;
    int gr = th - 2 + rr, gc = tw - 2 + cc;
    float v = (gr>=0 && gr<64 && gc>=0 && gc<64)
              ? c2buf[(((size_t)b*32 + cin) << 12) + (gr<<6) + gc] : 0.f;
    sc2[pxh*36 + cin] = v;
  }
  __syncthreads();
  // conv3 on 10x10 halo region; wave w -> couts 2w..2w+1
  for (int half = 0; half < 2; half++) {
    int px = l + (half << 6);
    if (px < 100) {
      int i = px / 10, j = px - i*10;
      int gy = th - 1 + i, gx = tw - 1 + j;
      bool inb = (gy>=0 && gy<64 && gx>=0 && gx<64);
      int co0 = w << 1;
      const float* w0p = c3w + (size_t)(co0+0)*288;
      const float* w1p = c3w + (size_t)(co0+1)*288;
      float acc0 = c3b[co0+0], acc1 = c3b[co0+1];
#pragma unroll
      for (int di=0; di<3; di++)
#pragma unroll
        for (int dj=0; dj<3; dj++) {
          int tlin = di*3 + dj;
          const float* vp = sc2 + ((i+di)*12 + j+dj)*36;
#pragma unroll
          for (int c4=0; c4<8; c4++) {
            float4 v = *(const float4*)(vp + (c4<<2));
            int wi = (c4<<2)*9 + tlin;
            acc0 = fmaf(v.x, w0p[wi], acc0);     acc1 = fmaf(v.x, w1p[wi], acc1);
            acc0 = fmaf(v.y, w0p[wi+9], acc0);   acc1 = fmaf(v.y, w1p[wi+9], acc1);
            acc0 = fmaf(v.z, w0p[wi+18], acc0);  acc1 = fmaf(v.z, w1p[wi+18], acc1);
            acc0 = fmaf(v.w, w0p[wi+27], acc0);  acc1 = fmaf(v.w, w1p[wi+27], acc1);
          }
        }
      sc3[px*20 + co0]     = inb ? tanhf(acc0) : 0.f;
      sc3[px*20 + co0 + 1] = inb ? tanhf(acc1) : 0.f;
    }
  }
  __syncthreads();
  if (tid < 64) {
    int py = tid >> 3, px = tid & 7;
    float acc = c4b[0];
#pragma unroll
    for (int di=0; di<3; di++)
#pragma unroll
      for (int dj=0; dj<3; dj++) {
        int tlin = di*3 + dj;
        const float* vp = sc3 + ((py+di)*10 + px+dj)*20;
#pragma unroll
        for (int c4=0; c4<4; c4++) {
          float4 v = *(const float4*)(vp + (c4<<2));
          int wi = (c4<<2)*9 + tlin;
          acc = fmaf(v.x, c4w[wi], acc);
          acc = fmaf(v.y, c4w[wi+9], acc);
          acc = fmaf(v.z, c4w[wi+18], acc);
          acc = fmaf(v.w, c4w[wi+27], acc);
        }
      }
    fbuf[b*NPIX + ((th+py)<<6) + (tw+px)] = acc;
  }
}

// ===== K3: per-batch sort: wave bitonic (256-runs) + merge-path =====
__global__ __launch_bounds__(1024) void sort2_k(const float* __restrict__ f,
    float* __restrict__ sval, int* __restrict__ sidx) {
  int b = blockIdx.x;
  int tid = threadIdx.x;
  int l = tid & 63, w = tid >> 6;
  __shared__ unsigned long long Ab[NPIX];
  __shared__ unsigned long long Bb[NPIX];
  const float* fb = f + b*NPIX;
  unsigned long long key[4];
#pragma unroll
  for (int r=0;r<4;r++) {
    unsigned e = (w<<8) + (r<<6) + l;
    float v = fb[e];
    unsigned u = __float_as_uint(v);
    u ^= (u >> 31) ? 0xFFFFFFFFu : 0x80000000u;   // order-preserving flip
    key[r] = (((unsigned long long)u) << 32) | e;
  }
  for (unsigned k = 2; k <= 256; k <<= 1) {
    for (unsigned j = k >> 1; j > 0; j >>= 1) {
      if (j >= 64) {
        unsigned rj = j >> 6;
#pragma unroll
        for (int r=0;r<4;r++) {
          int pr = r ^ (int)rj;
          if (pr > r) {
            unsigned e = (w<<8)+((unsigned)r<<6)+l;
            bool up = ((e & k & 255u) == 0);
            unsigned long long a = key[r], c = key[pr];
            bool sw = up ? (c < a) : (c > a);
            if (sw) { key[r] = c; key[pr] = a; }
          }
        }
      } else {
#pragma unroll
        for (int r=0;r<4;r++) {
          unsigned e = (w<<8)+((unsigned)r<<6)+l;
          unsigned long long a = key[r];
          unsigned long long p = shflx64(a, (int)j);
          bool up = ((e & k & 255u) == 0);
          bool keepmin = ((e & j) == 0) == up;
          key[r] = (keepmin ? (p < a) : (p > a)) ? p : a;
        }
      }
    }
  }
#pragma unroll
  for (int r=0;r<4;r++) Ab[(w<<8)+(r<<6)+l] = key[r];
  __syncthreads();
  unsigned long long* src = Ab;
  unsigned long long* dst = Bb;
  for (int lg = 8; lg <= 11; lg++) {
    const int L = 1 << lg;
    int p0 = tid << 2;
    int ri = p0 >> lg;
    int base = (ri ^ 1) << lg;
    int mbase = ((ri >> 1) << (lg + 1)) + (p0 & (L - 1));
    unsigned long long kk[4];
    int lo[4], hi[4];
#pragma unroll
    for (int r=0;r<4;r++) { kk[r] = src[p0 + r]; lo[r] = 0; hi[r] = L; }
    for (int s = 0; s <= lg; s++) {
#pragma unroll
      for (int r=0;r<4;r++) {
        if (lo[r] < hi[r]) {
          int mid = (lo[r] + hi[r]) >> 1;
          if (src[base + mid] < kk[r]) lo[r] = mid + 1; else hi[r] = mid;
        }
      }
    }
#pragma unroll
    for (int r=0;r<4;r++) dst[mbase + r + lo[r]] = kk[r];
    __syncthreads();
    unsigned long long* t = src; src = dst; dst = t;
  }
#pragma unroll
  for (int r=0;r<4;r++) {
    int p = (tid << 2) + r;
    unsigned long long kk = src[p];
    unsigned u = (unsigned)(kk >> 32);
    u ^= (u >> 31) ? 0x80000000u : 0xFFFFFFFFu;   // un-flip
    sval[b*NPIX + p] = __uint_as_float(u);
    sidx[b*NPIX + p] = (int)(kk & 0xFFFFFFFFu);
  }
}

// ===== K4: KNN (wave/point ILP-4) + BN1 moment partials =====
__global__ __launch_bounds__(512) void knn4_k(const float* __restrict__ f,
    const float* __restrict__ sval, const int* __restrict__ sidx,
    float* __restrict__ dout, double* __restrict__ part1) {
  const int tid = threadIdx.x, blk = blockIdx.x;   // 512 blocks
  const int l = tid & 63, w = tid >> 6;            // 8 waves
  const int bq = blk >> 7;                          // 128 blocks per batch
  const float* svb = sval + (bq << 12);
  const int*   sib = sidx + (bq << 12);
  const float* fB  = f + (bq << 12);
  double a0=0, a1=0, a2=0, a3=0, a4=0;
  unsigned long long kk[4];
  float fnp[4];
  int   sp[4];
#pragma unroll
  for (int p=0;p<4;p++) {
    int s = ((blk & 127) << 5) + (w << 2) + p;
    sp[p] = s;
    float fn = svb[s]; fnp[p] = fn;
    int start = s - 32;
    if (start < 0) start = 0;
    if (start > NPIX - 64) start = NPIX - 64;
    int q = start + l;
    float fm = svb[q];
    int   m  = sib[q];
    float sqn = __fmul_rn(fn, fn);
    float pr  = __fmul_rn(fn, fm);
    float dist = __fsub_rn(__fadd_rn(sqn, __fmul_rn(fm, fm)), __fmul_rn(2.0f, pr));
    unsigned u = __float_as_uint(dist);
    u ^= (u >> 31) ? 0xFFFFFFFFu : 0x80000000u;
    kk[p] = (((unsigned long long)u) << 32) | (unsigned)m;
  }
#pragma unroll
  for (int k = 2; k <= 64; k <<= 1)
#pragma unroll
    for (int j = k >> 1; j > 0; j >>= 1) {
#pragma unroll
      for (int p=0;p<4;p++) {
        unsigned long long pp = shflx64(kk[p], j);
        bool up = ((l & k) == 0);
        bool keepmin = ((l & j) == 0) == up;
        kk[p] = (keepmin ? (pp < kk[p]) : (pp > kk[p])) ? pp : kk[p];
      }
    }
#pragma unroll
  for (int p=0;p<4;p++) {
    int mr = (int)(kk[p] & 0xFFFFFFFFu);
    float fn = fnp[p];
    float d = __fsub_rn(fB[mr], fn);       // knn - x1, rank l
    int n = sib[sp[p]];
    if (l >= 1 && l <= 20)
      dout[(size_t)((bq<<12) + n)*KN + (l-1)] = d;
    float dm = (l >= 1 && l <= 20) ? d : 0.f;
    a2 += (double)dm;
    a3 += (double)dm * (double)dm;
    a4 += (double)fn * (double)dm;
    if (l == 0) { a0 += (double)fn; a1 += (double)fn * (double)fn; }
  }
  double v[5] = {a0, a1, a2, a3, a4};
#pragma unroll
  for (int qi=0; qi<5; qi++)
    for (int off=32; off>0; off>>=1) v[qi] += __shfl_down(v[qi], off, 64);
  __shared__ double sred[8][5];
  if (l == 0)
#pragma unroll
    for (int qi=0; qi<5; qi++) sred[w][qi] = v[qi];
  __syncthreads();
  if (tid == 0) {
#pragma unroll
    for (int qi=0; qi<5; qi++) {
      double s = 0.0;
#pragma unroll
      for (int ww=0; ww<8; ww++) s += sred[ww][qi];
      part1[blk*5 + qi] = s;
    }
  }
}

// ===== K5: redundant BN1 fold + per-branch o_pre max/min + BN2 partials =====
__global__ __launch_bounds__(64) void branch_k(const float* __restrict__ f,
    const float* __restrict__ dw, const double* __restrict__ part1,
    const float* __restrict__ ew1, const float* __restrict__ eb1,
    const float* __restrict__ eg1, const float* __restrict__ ebt1,
    const float* __restrict__ ew2, const float* __restrict__ eb2,
    float* __restrict__ maxo, float* __restrict__ mino,
    double* __restrict__ part2) {
  const int l = threadIdx.x;
  const int blk = blockIdx.x, br = blockIdx.y;
  double a[5] = {0,0,0,0,0};
  for (int b2 = l; b2 < 512; b2 += 64)
#pragma unroll
    for (int q=0;q<5;q++) a[q] += part1[b2*5+q];
#pragma unroll
  for (int q=0;q<5;q++)
    for (int off=32; off>0; off>>=1) a[q] += __shfl_down(a[q], off, 64);
#pragma unroll
  for (int q=0;q<5;q++) a[q] = __shfl(a[q], 0, 64);
  double Ef = a[0]/16384.0, Eff = a[1]/16384.0;
  double Ed = a[2]/MTOT, Edd = a[3]/MTOT, Efd = a[4]/MTOT;
  double Vf = Eff - Ef*Ef, Vd = Edd - Ed*Ed, Cfd = Efd - Ef*Ed;
  float sA[16], sB[16], sC[16], sW[16];
#pragma unroll
  for (int c=0;c<16;c++) {
    int idx = br*16 + c;
    double w0 = (double)ew1[idx*2+0], w1 = (double)ew1[idx*2+1];
    double b1 = (double)eb1[idx];
    double m1 = w0*Ef + w1*Ed + b1;
    double v1 = w0*w0*Vf + 2.0*w0*w1*Cfd + w1*w1*Vd;
    double r1 = 1.0 / sqrt(v1 + 1e-5);
    double g = (double)eg1[idx];
    sA[c] = (float)(g*r1*w0);
    sB[c] = (float)(g*r1*w1);
    sC[c] = (float)(g*r1*(b1 - m1) + (double)ebt1[idx]);
    sW[c] = ew2[idx];
  }
  int row = (blk << 6) + l;
  float fv = f[row];
  const float* dd = dw + (size_t)row*KN;
  float b2v = eb2[br];
  float P[16];
#pragma unroll
  for (int c=0;c<16;c++) P[c] = fmaf(sA[c], fv, sC[c]);
  float mx = -INFINITY, mn = INFINITY;
  double s = 0.0, s2 = 0.0;
  for (int k=0;k<KN;k++) {
    float d = dd[k];
    float t = b2v;
#pragma unroll
    for (int c=0;c<16;c++)
      t = fmaf(sW[c], fmaxf(fmaf(sB[c], d, P[c]), 0.f), t);
    mx = fmaxf(mx, t);
    mn = fminf(mn, t);
    double td = (double)t;
    s += td; s2 += td*td;
  }
  maxo[br*16384 + row] = mx;
  mino[br*16384 + row] = mn;
#pragma unroll
  for (int off=32; off>0; off>>=1) {
    s  += __shfl_down(s, off, 64);
    s2 += __shfl_down(s2, off, 64);
  }
  if (l == 0) {
    part2[(br*256 + blk)*2 + 0] = s;
    part2[(br*256 + blk)*2 + 1] = s2;
  }
}

// ===== K6: redundant BN2 fold + pixel shuffle + sigmoid =====
__global__ __launch_bounds__(256) void out_k(const float* __restrict__ f,
    const float* __restrict__ maxo, const float* __restrict__ mino,
    const double* __restrict__ part2,
    const float* __restrict__ eg2, const float* __restrict__ ebt2,
    float* __restrict__ out) {
  __shared__ float c2c[3][2];
  const int tid = threadIdx.x, blk = blockIdx.x;
  const int l = tid & 63, w = tid >> 6;
  if (w < 3) {
    int br = w;
    double s = 0.0, s2 = 0.0;
#pragma unroll
    for (int i=0;i<4;i++) {
      int bb = l + (i << 6);
      s  += part2[(br*256 + bb)*2 + 0];
      s2 += part2[(br*256 + bb)*2 + 1];
    }
#pragma unroll
    for (int off=32; off>0; off>>=1) {
      s  += __shfl_down(s, off, 64);
      s2 += __shfl_down(s2, off, 64);
    }
    if (l == 0) {
      double mean = s / MTOT;
      double var = s2 / MTOT - mean*mean;
      double r2 = 1.0 / sqrt(var + 1e-5);
      double sc = (double)eg2[br] * r2;
      c2c[br][0] = (float)sc;
      c2c[br][1] = (float)((double)ebt2[br] - sc*mean);
    }
  }
  __syncthreads();
  int tg = (blk << 8) + tid;     // 65536
  int bo = tg >> 14;
  int y = (tg >> 7) & 127, xx = tg & 127;
  int n = ((y>>1)<<6) + (xx>>1);
  int ch = ((y&1)<<1) + (xx&1);
  float v;
  if (ch == 0) {
    v = f[bo*NPIX + n];
  } else {
    int br = ch - 1;
    float sc = c2c[br][0], sh = c2c[br][1];
    float base = (sc >= 0.f) ? maxo[br*16384 + bo*NPIX + n]
                             : mino[br*16384 + bo*NPIX + n];
    v = fmaxf(fmaf(sc, base, sh), 0.f);
  }
  out[tg] = 1.f / (1.f + expf(-v));
}

extern "C" void kernel_launch(void* const* d_in, const int* in_sizes, int n_in,
                              void* d_out, int out_size, void* d_ws, size_t ws_size,
                              hipStream_t stream) {
  (void)in_sizes; (void)n_in; (void)out_size; (void)ws_size;
  const float* x    = (const float*)d_in[0];
  const float* c1w  = (const float*)d_in[1];
  const float* c1b  = (const float*)d_in[2];
  const float* c2w  = (const float*)d_in[3];
  const float* c2b  = (const float*)d_in[4];
  const float* c3w  = (const float*)d_in[5];
  const float* c3b  = (const float*)d_in[6];
  const float* c4w  = (const float*)d_in[7];
  const float* c4b  = (const float*)d_in[8];
  const float* ew1  = (const float*)d_in[9];
  const float* eb1  = (const float*)d_in[10];
  const float* eg1  = (const float*)d_in[11];
  const float* ebt1 = (const float*)d_in[12];
  const float* ew2  = (const float*)d_in[13];
  const float* eb2  = (const float*)d_in[14];
  const float* eg2  = (const float*)d_in[15];
  const float* ebt2 = (const float*)d_in[16];
  float* out = (float*)d_out;
  float* ws  = (float*)d_ws;

  float*  c2buf = ws;                       // 524288 floats
  float*  fbuf  = ws + 524288;              // 16384
  float*  dw    = ws + 540672;              // 327680
  float*  sval  = ws + 868352;              // 16384
  int*    sidx  = (int*)(ws + 884736);      // 16384
  float*  maxo  = ws + 901120;              // 49152
  float*  mino  = ws + 950272;              // 49152
  double* part1 = (double*)(ws + 999424);   // 512*5 doubles
  double* part2 = (double*)(ws + 1004544);  // 256*3*2 doubles

  conv12_k<<<dim3(4,64), 512, 0, stream>>>(x, c1w, c1b, c2w, c2b, c2buf);
  conv34_k<<<dim3(4,64), 512, 0, stream>>>(c2buf, c3w, c3b, c4w, c4b, fbuf);
  sort2_k<<<4, 1024, 0, stream>>>(fbuf, sval, sidx);
  knn4_k<<<512, 512, 0, stream>>>(fbuf, sval, sidx, dw, part1);
  branch_k<<<dim3(256,3), 64, 0, stream>>>(fbuf, dw, part1,
      ew1, eb1, eg1, ebt1, ew2, eb2, maxo, mino, part2);
  out_k<<<256, 256, 0, stream>>>(fbuf, maxo, mino, part2, eg2, ebt2, out);
}

// Round 13
// 121.697 us; speedup vs baseline: 2.7115x; 2.7115x over previous
//
#include <hip/hip_runtime.h>
#include <math.h>

#define NPIX 4096
#define KN 20
#define MTOT 327680.0    // B*N*K

__device__ inline unsigned long long shflx64(unsigned long long v, int m) {
  unsigned lo = (unsigned)v, hi = (unsigned)(v >> 32);
  lo = __shfl_xor(lo, m, 64);
  hi = __shfl_xor(hi, m, 64);
  return (((unsigned long long)hi) << 32) | lo;
}

// ===== K1: conv1 (5x5,1->64,tanh, zero-outside) + conv2 (3x3,64->32,tanh) =====
// Channels-last LDS (px-major, 68-stride) -> conv2 reads float4; unroll capped
// (runtime tap loop) to avoid the round-12 spill disaster.
__global__ __launch_bounds__(512) void conv12_k(const float* __restrict__ x,
    const float* __restrict__ c1w, const float* __restrict__ c1b,
    const float* __restrict__ c2w, const float* __restrict__ c2b,
    float* __restrict__ c2buf) {
  __shared__ float sx[230];          // 14x14 halo, stride 16
  __shared__ float sc1[6800];        // 100 px (10x10) x 68 (64 ch + pad)
  const int tid = threadIdx.x;
  const int l = tid & 63;
  const int w = __builtin_amdgcn_readfirstlane(tid >> 6);   // 8 waves, uniform
  const int b = blockIdx.x, tile = blockIdx.y;
  const int th = (tile >> 3) << 3, tw = (tile & 7) << 3;

  for (int i = tid; i < 196; i += 512) {
    int r = i / 14, c = i - r*14;
    int gr = th - 3 + r, gc = tw - 3 + c;
    sx[r*16 + c] = (gr>=0 && gr<64 && gc>=0 && gc<64) ? x[b*NPIX + (gr<<6) + gc] : 0.f;
  }
  __syncthreads();
  // conv1 on 10x10 halo region; wave w -> couts w*8..+7; channels-last store
  for (int half = 0; half < 2; half++) {
    int px = l + (half << 6);
    if (px < 100) {
      int i = px / 10, j = px - i*10;
      int gy = th - 1 + i, gx = tw - 1 + j;
      bool inb = (gy>=0 && gy<64 && gx>=0 && gx<64);
      for (int cc = 0; cc < 8; cc++) {
        int co = (w << 3) + cc;
        float acc = c1b[co];
#pragma unroll
        for (int di=0; di<5; di++)
#pragma unroll
          for (int dj=0; dj<5; dj++)
            acc = fmaf(sx[(i+di)*16 + j+dj], c1w[co*25 + di*5 + dj], acc);
        sc1[px*68 + co] = inb ? tanhf(acc) : 0.f;
      }
    }
  }
  __syncthreads();
  // conv2 exact 8x8: lane -> pixel; wave -> couts w*4..+3; float4 cin reads.
  {
    int py = l >> 3, px2 = l & 7;
    int co0 = w << 2;
    const float* wbase = c2w + (size_t)co0 * 576;
    float acc0 = c2b[co0+0], acc1 = c2b[co0+1], acc2 = c2b[co0+2], acc3 = c2b[co0+3];
#pragma unroll 1
    for (int t = 0; t < 9; ++t) {               // runtime tap loop: low reg pressure
      int di = t / 3, dj = t - di*3;
      const float* vp = sc1 + ((py+di)*10 + px2+dj)*68;
      const float* wt = wbase + t;
#pragma unroll 4
      for (int c4 = 0; c4 < 16; ++c4) {
        float4 v = *(const float4*)(vp + (c4<<2));
        int wi = (c4<<2)*9;
        acc0 = fmaf(v.x, wt[wi       ], acc0);
        acc1 = fmaf(v.x, wt[wi+576   ], acc1);
        acc2 = fmaf(v.x, wt[wi+1152  ], acc2);
        acc3 = fmaf(v.x, wt[wi+1728  ], acc3);
        acc0 = fmaf(v.y, wt[wi+9     ], acc0);
        acc1 = fmaf(v.y, wt[wi+585   ], acc1);
        acc2 = fmaf(v.y, wt[wi+1161  ], acc2);
        acc3 = fmaf(v.y, wt[wi+1737  ], acc3);
        acc0 = fmaf(v.z, wt[wi+18    ], acc0);
        acc1 = fmaf(v.z, wt[wi+594   ], acc1);
        acc2 = fmaf(v.z, wt[wi+1170  ], acc2);
        acc3 = fmaf(v.z, wt[wi+1746  ], acc3);
        acc0 = fmaf(v.w, wt[wi+27    ], acc0);
        acc1 = fmaf(v.w, wt[wi+603   ], acc1);
        acc2 = fmaf(v.w, wt[wi+1179  ], acc2);
        acc3 = fmaf(v.w, wt[wi+1755  ], acc3);
      }
    }
    size_t base = (((size_t)b*32 + co0) << 12) + ((th+py)<<6) + (tw+px2);
    c2buf[base]            = tanhf(acc0);
    c2buf[base + (1<<12)]  = tanhf(acc1);
    c2buf[base + (2<<12)]  = tanhf(acc2);
    c2buf[base + (3<<12)]  = tanhf(acc3);
  }
}

// ===== K2: conv3 (3x3,32->16,tanh, zero-outside) + conv4 (3x3,16->1) =====
// Channels-last LDS, float4 cin reads, unroll capped.
__global__ __launch_bounds__(512) void conv34_k(const float* __restrict__ c2buf,
    const float* __restrict__ c3w, const float* __restrict__ c3b,
    const float* __restrict__ c4w, const float* __restrict__ c4b,
    float* __restrict__ fbuf) {
  __shared__ float sc2[5184];        // 144 px (12x12) x 36 (32 ch + pad)
  __shared__ float sc3[2000];        // 100 px (10x10) x 20 (16 ch + pad)
  const int tid = threadIdx.x;
  const int l = tid & 63;
  const int w = __builtin_amdgcn_readfirstlane(tid >> 6);
  const int b = blockIdx.x, tile = blockIdx.y;
  const int th = (tile >> 3) << 3, tw = (tile & 7) << 3;

  for (int i = tid; i < 4608; i += 512) {
    int cin = i / 144, pxh = i - cin*144;
    int rr = pxh / 12, cc = pxh - rr*12;
    int gr = th - 2 + rr, gc = tw - 2 + cc;
    float v = (gr>=0 && gr<64 && gc>=0 && gc<64)
              ? c2buf[(((size_t)b*32 + cin) << 12) + (gr<<6) + gc] : 0.f;
    sc2[pxh*36 + cin] = v;
  }
  __syncthreads();
  // conv3 on 10x10 halo region; wave w -> couts 2w..2w+1
  for (int half = 0; half < 2; half++) {
    int px = l + (half << 6);
    if (px < 100) {
      int i = px / 10, j = px - i*10;
      int gy = th - 1 + i, gx = tw - 1 + j;
      bool inb = (gy>=0 && gy<64 && gx>=0 && gx<64);
      int co0 = w << 1;
      const float* wbase = c3w + (size_t)co0 * 288;
      float acc0 = c3b[co0+0], acc1 = c3b[co0+1];
#pragma unroll 1
      for (int t = 0; t < 9; ++t) {
        int di = t / 3, dj = t - di*3;
        const float* vp = sc2 + ((i+di)*12 + j+dj)*36;
        const float* wt = wbase + t;
#pragma unroll 4
        for (int c4 = 0; c4 < 8; ++c4) {
          float4 v = *(const float4*)(vp + (c4<<2));
          int wi = (c4<<2)*9;
          acc0 = fmaf(v.x, wt[wi      ], acc0);
          acc1 = fmaf(v.x, wt[wi+288  ], acc1);
          acc0 = fmaf(v.y, wt[wi+9    ], acc0);
          acc1 = fmaf(v.y, wt[wi+297  ], acc1);
          acc0 = fmaf(v.z, wt[wi+18   ], acc0);
          acc1 = fmaf(v.z, wt[wi+306  ], acc1);
          acc0 = fmaf(v.w, wt[wi+27   ], acc0);
          acc1 = fmaf(v.w, wt[wi+315  ], acc1);
        }
      }
      sc3[px*20 + co0]     = inb ? tanhf(acc0) : 0.f;
      sc3[px*20 + co0 + 1] = inb ? tanhf(acc1) : 0.f;
    }
  }
  __syncthreads();
  if (tid < 64) {
    int py = tid >> 3, px = tid & 7;
    float acc = c4b[0];
#pragma unroll 1
    for (int t = 0; t < 9; ++t) {
      int di = t / 3, dj = t - di*3;
      const float* vp = sc3 + ((py+di)*10 + px+dj)*20;
#pragma unroll 4
      for (int c4 = 0; c4 < 4; ++c4) {
        float4 v = *(const float4*)(vp + (c4<<2));
        int wi = (c4<<2)*9 + t;
        acc = fmaf(v.x, c4w[wi], acc);
        acc = fmaf(v.y, c4w[wi+9], acc);
        acc = fmaf(v.z, c4w[wi+18], acc);
        acc = fmaf(v.w, c4w[wi+27], acc);
      }
    }
    fbuf[b*NPIX + ((th+py)<<6) + (tw+px)] = acc;
  }
}

// ===== K3: per-batch sort: wave bitonic (256-runs) + merge-path =====
__global__ __launch_bounds__(1024) void sort2_k(const float* __restrict__ f,
    float* __restrict__ sval, int* __restrict__ sidx) {
  int b = blockIdx.x;
  int tid = threadIdx.x;
  int l = tid & 63, w = tid >> 6;
  __shared__ unsigned long long Ab[NPIX];
  __shared__ unsigned long long Bb[NPIX];
  const float* fb = f + b*NPIX;
  unsigned long long key[4];
#pragma unroll
  for (int r=0;r<4;r++) {
    unsigned e = (w<<8) + (r<<6) + l;
    float v = fb[e];
    unsigned u = __float_as_uint(v);
    u ^= (u >> 31) ? 0xFFFFFFFFu : 0x80000000u;   // order-preserving flip
    key[r] = (((unsigned long long)u) << 32) | e;
  }
  for (unsigned k = 2; k <= 256; k <<= 1) {
    for (unsigned j = k >> 1; j > 0; j >>= 1) {
      if (j >= 64) {
        unsigned rj = j >> 6;
#pragma unroll
        for (int r=0;r<4;r++) {
          int pr = r ^ (int)rj;
          if (pr > r) {
            unsigned e = (w<<8)+((unsigned)r<<6)+l;
            bool up = ((e & k & 255u) == 0);
            unsigned long long a = key[r], c = key[pr];
            bool sw = up ? (c < a) : (c > a);
            if (sw) { key[r] = c; key[pr] = a; }
          }
        }
      } else {
#pragma unroll
        for (int r=0;r<4;r++) {
          unsigned e = (w<<8)+((unsigned)r<<6)+l;
          unsigned long long a = key[r];
          unsigned long long p = shflx64(a, (int)j);
          bool up = ((e & k & 255u) == 0);
          bool keepmin = ((e & j) == 0) == up;
          key[r] = (keepmin ? (p < a) : (p > a)) ? p : a;
        }
      }
    }
  }
#pragma unroll
  for (int r=0;r<4;r++) Ab[(w<<8)+(r<<6)+l] = key[r];
  __syncthreads();
  unsigned long long* src = Ab;
  unsigned long long* dst = Bb;
  for (int lg = 8; lg <= 11; lg++) {
    const int L = 1 << lg;
    int p0 = tid << 2;
    int ri = p0 >> lg;
    int base = (ri ^ 1) << lg;
    int mbase = ((ri >> 1) << (lg + 1)) + (p0 & (L - 1));
    unsigned long long kk[4];
    int lo[4], hi[4];
#pragma unroll
    for (int r=0;r<4;r++) { kk[r] = src[p0 + r]; lo[r] = 0; hi[r] = L; }
    for (int s = 0; s <= lg; s++) {
#pragma unroll
      for (int r=0;r<4;r++) {
        if (lo[r] < hi[r]) {
          int mid = (lo[r] + hi[r]) >> 1;
          if (src[base + mid] < kk[r]) lo[r] = mid + 1; else hi[r] = mid;
        }
      }
    }
#pragma unroll
    for (int r=0;r<4;r++) dst[mbase + r + lo[r]] = kk[r];
    __syncthreads();
    unsigned long long* t = src; src = dst; dst = t;
  }
#pragma unroll
  for (int r=0;r<4;r++) {
    int p = (tid << 2) + r;
    unsigned long long kk = src[p];
    unsigned u = (unsigned)(kk >> 32);
    u ^= (u >> 31) ? 0x80000000u : 0xFFFFFFFFu;   // un-flip
    sval[b*NPIX + p] = __uint_as_float(u);
    sidx[b*NPIX + p] = (int)(kk & 0xFFFFFFFFu);
  }
}

// ===== K4: KNN (wave/point ILP-4) + BN1 moment partials =====
__global__ __launch_bounds__(512) void knn4_k(const float* __restrict__ f,
    const float* __restrict__ sval, const int* __restrict__ sidx,
    float* __restrict__ dout, double* __restrict__ part1) {
  const int tid = threadIdx.x, blk = blockIdx.x;   // 512 blocks
  const int l = tid & 63, w = tid >> 6;            // 8 waves
  const int bq = blk >> 7;                          // 128 blocks per batch
  const float* svb = sval + (bq << 12);
  const int*   sib = sidx + (bq << 12);
  const float* fB  = f + (bq << 12);
  double a0=0, a1=0, a2=0, a3=0, a4=0;
  unsigned long long kk[4];
  float fnp[4];
  int   sp[4];
#pragma unroll
  for (int p=0;p<4;p++) {
    int s = ((blk & 127) << 5) + (w << 2) + p;
    sp[p] = s;
    float fn = svb[s]; fnp[p] = fn;
    int start = s - 32;
    if (start < 0) start = 0;
    if (start > NPIX - 64) start = NPIX - 64;
    int q = start + l;
    float fm = svb[q];
    int   m  = sib[q];
    float sqn = __fmul_rn(fn, fn);
    float pr  = __fmul_rn(fn, fm);
    float dist = __fsub_rn(__fadd_rn(sqn, __fmul_rn(fm, fm)), __fmul_rn(2.0f, pr));
    unsigned u = __float_as_uint(dist);
    u ^= (u >> 31) ? 0xFFFFFFFFu : 0x80000000u;
    kk[p] = (((unsigned long long)u) << 32) | (unsigned)m;
  }
#pragma unroll
  for (int k = 2; k <= 64; k <<= 1)
#pragma unroll
    for (int j = k >> 1; j > 0; j >>= 1) {
#pragma unroll
      for (int p=0;p<4;p++) {
        unsigned long long pp = shflx64(kk[p], j);
        bool up = ((l & k) == 0);
        bool keepmin = ((l & j) == 0) == up;
        kk[p] = (keepmin ? (pp < kk[p]) : (pp > kk[p])) ? pp : kk[p];
      }
    }
#pragma unroll
  for (int p=0;p<4;p++) {
    int mr = (int)(kk[p] & 0xFFFFFFFFu);
    float fn = fnp[p];
    float d = __fsub_rn(fB[mr], fn);       // knn - x1, rank l
    int n = sib[sp[p]];
    if (l >= 1 && l <= 20)
      dout[(size_t)((bq<<12) + n)*KN + (l-1)] = d;
    float dm = (l >= 1 && l <= 20) ? d : 0.f;
    a2 += (double)dm;
    a3 += (double)dm * (double)dm;
    a4 += (double)fn * (double)dm;
    if (l == 0) { a0 += (double)fn; a1 += (double)fn * (double)fn; }
  }
  double v[5] = {a0, a1, a2, a3, a4};
#pragma unroll
  for (int qi=0; qi<5; qi++)
    for (int off=32; off>0; off>>=1) v[qi] += __shfl_down(v[qi], off, 64);
  __shared__ double sred[8][5];
  if (l == 0)
#pragma unroll
    for (int qi=0; qi<5; qi++) sred[w][qi] = v[qi];
  __syncthreads();
  if (tid == 0) {
#pragma unroll
    for (int qi=0; qi<5; qi++) {
      double s = 0.0;
#pragma unroll
      for (int ww=0; ww<8; ww++) s += sred[ww][qi];
      part1[blk*5 + qi] = s;
    }
  }
}

// ===== K5: redundant BN1 fold + per-branch o_pre max/min + BN2 partials =====
__global__ __launch_bounds__(64) void branch_k(const float* __restrict__ f,
    const float* __restrict__ dw, const double* __restrict__ part1,
    const float* __restrict__ ew1, const float* __restrict__ eb1,
    const float* __restrict__ eg1, const float* __restrict__ ebt1,
    const float* __restrict__ ew2, const float* __restrict__ eb2,
    float* __restrict__ maxo, float* __restrict__ mino,
    double* __restrict__ part2) {
  const int l = threadIdx.x;
  const int blk = blockIdx.x, br = blockIdx.y;
  double a[5] = {0,0,0,0,0};
  for (int b2 = l; b2 < 512; b2 += 64)
#pragma unroll
    for (int q=0;q<5;q++) a[q] += part1[b2*5+q];
#pragma unroll
  for (int q=0;q<5;q++)
    for (int off=32; off>0; off>>=1) a[q] += __shfl_down(a[q], off, 64);
#pragma unroll
  for (int q=0;q<5;q++) a[q] = __shfl(a[q], 0, 64);
  double Ef = a[0]/16384.0, Eff = a[1]/16384.0;
  double Ed = a[2]/MTOT, Edd = a[3]/MTOT, Efd = a[4]/MTOT;
  double Vf = Eff - Ef*Ef, Vd = Edd - Ed*Ed, Cfd = Efd - Ef*Ed;
  float sA[16], sB[16], sC[16], sW[16];
#pragma unroll
  for (int c=0;c<16;c++) {
    int idx = br*16 + c;
    double w0 = (double)ew1[idx*2+0], w1 = (double)ew1[idx*2+1];
    double b1 = (double)eb1[idx];
    double m1 = w0*Ef + w1*Ed + b1;
    double v1 = w0*w0*Vf + 2.0*w0*w1*Cfd + w1*w1*Vd;
    double r1 = 1.0 / sqrt(v1 + 1e-5);
    double g = (double)eg1[idx];
    sA[c] = (float)(g*r1*w0);
    sB[c] = (float)(g*r1*w1);
    sC[c] = (float)(g*r1*(b1 - m1) + (double)ebt1[idx]);
    sW[c] = ew2[idx];
  }
  int row = (blk << 6) + l;
  float fv = f[row];
  const float* dd = dw + (size_t)row*KN;
  float b2v = eb2[br];
  float P[16];
#pragma unroll
  for (int c=0;c<16;c++) P[c] = fmaf(sA[c], fv, sC[c]);
  float mx = -INFINITY, mn = INFINITY;
  double s = 0.0, s2 = 0.0;
  for (int k=0;k<KN;k++) {
    float d = dd[k];
    float t = b2v;
#pragma unroll
    for (int c=0;c<16;c++)
      t = fmaf(sW[c], fmaxf(fmaf(sB[c], d, P[c]), 0.f), t);
    mx = fmaxf(mx, t);
    mn = fminf(mn, t);
    double td = (double)t;
    s += td; s2 += td*td;
  }
  maxo[br*16384 + row] = mx;
  mino[br*16384 + row] = mn;
#pragma unroll
  for (int off=32; off>0; off>>=1) {
    s  += __shfl_down(s, off, 64);
    s2 += __shfl_down(s2, off, 64);
  }
  if (l == 0) {
    part2[(br*256 + blk)*2 + 0] = s;
    part2[(br*256 + blk)*2 + 1] = s2;
  }
}

// ===== K6: redundant BN2 fold + pixel shuffle + sigmoid =====
__global__ __launch_bounds__(256) void out_k(const float* __restrict__ f,
    const float* __restrict__ maxo, const float* __restrict__ mino,
    const double* __restrict__ part2,
    const float* __restrict__ eg2, const float* __restrict__ ebt2,
    float* __restrict__ out) {
  __shared__ float c2c[3][2];
  const int tid = threadIdx.x, blk = blockIdx.x;
  const int l = tid & 63, w = tid >> 6;
  if (w < 3) {
    int br = w;
    double s = 0.0, s2 = 0.0;
#pragma unroll
    for (int i=0;i<4;i++) {
      int bb = l + (i << 6);
      s  += part2[(br*256 + bb)*2 + 0];
      s2 += part2[(br*256 + bb)*2 + 1];
    }
#pragma unroll
    for (int off=32; off>0; off>>=1) {
      s  += __shfl_down(s, off, 64);
      s2 += __shfl_down(s2, off, 64);
    }
    if (l == 0) {
      double mean = s / MTOT;
      double var = s2 / MTOT - mean*mean;
      double r2 = 1.0 / sqrt(var + 1e-5);
      double sc = (double)eg2[br] * r2;
      c2c[br][0] = (float)sc;
      c2c[br][1] = (float)((double)ebt2[br] - sc*mean);
    }
  }
  __syncthreads();
  int tg = (blk << 8) + tid;     // 65536
  int bo = tg >> 14;
  int y = (tg >> 7) & 127, xx = tg & 127;
  int n = ((y>>1)<<6) + (xx>>1);
  int ch = ((y&1)<<1) + (xx&1);
  float v;
  if (ch == 0) {
    v = f[bo*NPIX + n];
  } else {
    int br = ch - 1;
    float sc = c2c[br][0], sh = c2c[br][1];
    float base = (sc >= 0.f) ? maxo[br*16384 + bo*NPIX + n]
                             : mino[br*16384 + bo*NPIX + n];
    v = fmaxf(fmaf(sc, base, sh), 0.f);
  }
  out[tg] = 1.f / (1.f + expf(-v));
}

extern "C" void kernel_launch(void* const* d_in, const int* in_sizes, int n_in,
                              void* d_out, int out_size, void* d_ws, size_t ws_size,
                              hipStream_t stream) {
  (void)in_sizes; (void)n_in; (void)out_size; (void)ws_size;
  const float* x    = (const float*)d_in[0];
  const float* c1w  = (const float*)d_in[1];
  const float* c1b  = (const float*)d_in[2];
  const float* c2w  = (const float*)d_in[3];
  const float* c2b  = (const float*)d_in[4];
  const float* c3w  = (const float*)d_in[5];
  const float* c3b  = (const float*)d_in[6];
  const float* c4w  = (const float*)d_in[7];
  const float* c4b  = (const float*)d_in[8];
  const float* ew1  = (const float*)d_in[9];
  const float* eb1  = (const float*)d_in[10];
  const float* eg1  = (const float*)d_in[11];
  const float* ebt1 = (const float*)d_in[12];
  const float* ew2  = (const float*)d_in[13];
  const float* eb2  = (const float*)d_in[14];
  const float* eg2  = (const float*)d_in[15];
  const float* ebt2 = (const float*)d_in[16];
  float* out = (float*)d_out;
  float* ws  = (float*)d_ws;

  float*  c2buf = ws;                       // 524288 floats
  float*  fbuf  = ws + 524288;              // 16384
  float*  dw    = ws + 540672;              // 327680
  float*  sval  = ws + 868352;              // 16384
  int*    sidx  = (int*)(ws + 884736);      // 16384
  float*  maxo  = ws + 901120;              // 49152
  float*  mino  = ws + 950272;              // 49152
  double* part1 = (double*)(ws + 999424);   // 512*5 doubles
  double* part2 = (double*)(ws + 1004544);  // 256*3*2 doubles

  conv12_k<<<dim3(4,64), 512, 0, stream>>>(x, c1w, c1b, c2w, c2b, c2buf);
  conv34_k<<<dim3(4,64), 512, 0, stream>>>(c2buf, c3w, c3b, c4w, c4b, fbuf);
  sort2_k<<<4, 1024, 0, stream>>>(fbuf, sval, sidx);
  knn4_k<<<512, 512, 0, stream>>>(fbuf, sval, sidx, dw, part1);
  branch_k<<<dim3(256,3), 64, 0, stream>>>(fbuf, dw, part1,
      ew1, eb1, eg1, ebt1, ew2, eb2, maxo, mino, part2);
  out_k<<<256, 256, 0, stream>>>(fbuf, maxo, mino, part2, eg2, ebt2, out);
}